// Round 1
// baseline (587.529 us; speedup 1.0000x reference)
//
#include <hip/hip_runtime.h>

// ---------------------------------------------------------------------------
// sxsGCN: h=[B=128,N=4096,3]; 3x { relu((adj@h)@W+b) }; then FC 12288->54->4096
// Strategy: bf16 MFMA GEMMs adj[4096x4096] @ H[4096 x B*F], H stored transposed
// [c = b*F+f][m] so B-operand staging is contiguous along K.
// ---------------------------------------------------------------------------

typedef __bf16 bf16x8 __attribute__((ext_vector_type(8)));
typedef float  f32x4  __attribute__((ext_vector_type(4)));

#define N_NODE 4096
#define BATCH  128

__device__ __forceinline__ void async_copy16(const void* gsrc, void* ldst) {
    __builtin_amdgcn_global_load_lds(
        (const __attribute__((address_space(1))) void*)gsrc,
        (__attribute__((address_space(3))) void*)ldst,
        16, 0, 0);
}

// adj fp32 -> bf16, 8 elems/thread
__global__ __launch_bounds__(256) void cast_adj_k(const float* __restrict__ A,
                                                  __bf16* __restrict__ AB) {
    const size_t i = (size_t)blockIdx.x * 256 + threadIdx.x;   // i-th group of 8
    const float4* a4 = (const float4*)A;
    float4 u = a4[i * 2];
    float4 v = a4[i * 2 + 1];
    bf16x8 o = { (__bf16)u.x, (__bf16)u.y, (__bf16)u.z, (__bf16)u.w,
                 (__bf16)v.x, (__bf16)v.y, (__bf16)v.z, (__bf16)v.w };
    *(bf16x8*)(AB + i * 8) = o;
}

// H0[c= b*3+f][m] = bf16(X[b][m*3+f]);  384*4096 elems, 1 per thread
__global__ __launch_bounds__(256) void build_h0_k(const float* __restrict__ X,
                                                  __bf16* __restrict__ H0) {
    const int idx = blockIdx.x * 256 + threadIdx.x;  // < 384*4096
    const int c = idx >> 12, m = idx & 4095;
    const int b = c / 3, f = c - b * 3;
    H0[idx] = (__bf16)X[(size_t)b * 12288 + m * 3 + f];
}

// C[m][c] = sum_k adjB[m][k] * Ht[c][k];  tile 64x64, 4 waves of 32x32.
// A-frag: A[m=lane&15][k=quad*8+j]; B-frag: B[k=quad*8+j][n=lane&15];
// C/D: col=lane&15, row=quad*4+reg  (learn_hip m89-verified layouts).
__global__ __launch_bounds__(256) void gemm_k(const __bf16* __restrict__ A,
                                              const __bf16* __restrict__ Bt,
                                              float* __restrict__ C, int Nc) {
    __shared__ __align__(16) __bf16 As[64 * 32];
    __shared__ __align__(16) __bf16 Bs[64 * 32];
    const int tx   = threadIdx.x;
    const int wave = tx >> 6, lane = tx & 63;
    const int quad = lane >> 4, lr = lane & 15;
    const int m0 = blockIdx.y * 64;
    const int c0 = blockIdx.x * 64;
    const int wm = wave >> 1, wn = wave & 1;   // 32x32 quadrant per wave

    // staging: thread t loads 16B for LDS byte offset t*16 (row t/4, k=(t%4)*8)
    const int srow  = tx >> 2;
    const int skoff = (tx & 3) * 8;
    const __bf16* gA = A  + (size_t)(m0 + srow) * 4096 + skoff;
    const __bf16* gB = Bt + (size_t)(c0 + srow) * 4096 + skoff;
    __bf16* lA = As + wave * 512;   // wave-uniform base; lane lands at +lane*16B
    __bf16* lB = Bs + wave * 512;

    f32x4 acc[2][2] = {};

    for (int k0 = 0; k0 < 4096; k0 += 32) {
        __syncthreads();                 // protect LDS against prior iter reads
        async_copy16(gA + k0, lA);
        async_copy16(gB + k0, lB);
        __syncthreads();                 // drains vmcnt -> LDS tiles ready
#pragma unroll
        for (int i = 0; i < 2; ++i) {
            bf16x8 af = *(const bf16x8*)(As + (wm * 32 + i * 16 + lr) * 32 + quad * 8);
#pragma unroll
            for (int j = 0; j < 2; ++j) {
                bf16x8 bfv = *(const bf16x8*)(Bs + (wn * 32 + j * 16 + lr) * 32 + quad * 8);
                acc[i][j] = __builtin_amdgcn_mfma_f32_16x16x32_bf16(af, bfv, acc[i][j], 0, 0, 0);
            }
        }
    }

#pragma unroll
    for (int i = 0; i < 2; ++i)
#pragma unroll
        for (int j = 0; j < 2; ++j)
#pragma unroll
            for (int r = 0; r < 4; ++r) {
                const int row = m0 + wm * 32 + i * 16 + quad * 4 + r;
                const int col = c0 + wn * 32 + j * 16 + lr;
                C[(size_t)row * Nc + col] = acc[i][j][r];
            }
}

// Hout[(b*FO+fo)][m] = relu( sum_fi C[m][b*FI+fi] * W[fi][fo] + bias[fo] )
template <int FI, int FO, typename OUT_T>
__global__ __launch_bounds__(256) void epi_k(const float* __restrict__ C,
                                             const float* __restrict__ W,
                                             const float* __restrict__ bias,
                                             OUT_T* __restrict__ Hout, int Ncin) {
    const int m = blockIdx.x * 256 + threadIdx.x;
    const int b = blockIdx.y;
    float in[FI];
#pragma unroll
    for (int fi = 0; fi < FI; ++fi) in[fi] = C[(size_t)m * Ncin + b * FI + fi];
#pragma unroll
    for (int fo = 0; fo < FO; ++fo) {
        float v = bias[fo];
#pragma unroll
        for (int fi = 0; fi < FI; ++fi) v += in[fi] * W[fi * FO + fo];
        v = fmaxf(v, 0.f);
        Hout[(size_t)(b * FO + fo) * N_NODE + m] = (OUT_T)v;
    }
}

// hid[b][j] = relu( sum_{n,f} H3[(b*3+f)][n] * Wfc[(n*3+f)*54+j] + bfc[j] )
// grid 32 blocks, 4 batches/block; 4 waves split the n-range; LDS reduce.
__global__ __launch_bounds__(256) void fc1_k(const float* __restrict__ H3,
                                             const float* __restrict__ Wfc,
                                             const float* __restrict__ bfc,
                                             float* __restrict__ hid) {
    const int tx = threadIdx.x;
    const int wv = tx >> 6;
    const int j  = tx & 63;
    const int b0 = blockIdx.x * 4;
    float a0 = 0.f, a1 = 0.f, a2 = 0.f, a3 = 0.f;
    if (j < 54) {
        const int n_begin = wv * 1024, n_end = n_begin + 1024;
        for (int n = n_begin; n < n_end; ++n) {
#pragma unroll
            for (int f = 0; f < 3; ++f) {
                float w  = Wfc[(n * 3 + f) * 54 + j];
                float x0 = H3[((size_t)((b0 + 0) * 3 + f)) * N_NODE + n];
                float x1 = H3[((size_t)((b0 + 1) * 3 + f)) * N_NODE + n];
                float x2 = H3[((size_t)((b0 + 2) * 3 + f)) * N_NODE + n];
                float x3 = H3[((size_t)((b0 + 3) * 3 + f)) * N_NODE + n];
                a0 += x0 * w; a1 += x1 * w; a2 += x2 * w; a3 += x3 * w;
            }
        }
    }
    __shared__ float red[4][4][64];
    red[wv][0][j] = a0; red[wv][1][j] = a1; red[wv][2][j] = a2; red[wv][3][j] = a3;
    __syncthreads();
    if (wv == 0 && j < 54) {
#pragma unroll
        for (int bs = 0; bs < 4; ++bs) {
            float s = red[0][bs][j] + red[1][bs][j] + red[2][bs][j] + red[3][bs][j] + bfc[j];
            hid[(b0 + bs) * 54 + j] = fmaxf(s, 0.f);
        }
    }
}

// out[b][a] = sum_j hid[b][j]*Wout[j][a] + bout[a];  4 batches/block
__global__ __launch_bounds__(256) void fc2_k(const float* __restrict__ hid,
                                             const float* __restrict__ Wout,
                                             const float* __restrict__ bout,
                                             float* __restrict__ out) {
    const int tx = threadIdx.x;
    const int a  = blockIdx.x * 256 + tx;
    const int b0 = blockIdx.y * 4;
    __shared__ float hs[4 * 54];
    if (tx < 216) hs[tx] = hid[b0 * 54 + tx];
    __syncthreads();
    float a0 = 0.f, a1 = 0.f, a2 = 0.f, a3 = 0.f;
    for (int j = 0; j < 54; ++j) {
        float w = Wout[(size_t)j * N_NODE + a];
        a0 += hs[0 * 54 + j] * w;
        a1 += hs[1 * 54 + j] * w;
        a2 += hs[2 * 54 + j] * w;
        a3 += hs[3 * 54 + j] * w;
    }
    float bo = bout[a];
    out[(size_t)(b0 + 0) * N_NODE + a] = a0 + bo;
    out[(size_t)(b0 + 1) * N_NODE + a] = a1 + bo;
    out[(size_t)(b0 + 2) * N_NODE + a] = a2 + bo;
    out[(size_t)(b0 + 3) * N_NODE + a] = a3 + bo;
}

extern "C" void kernel_launch(void* const* d_in, const int* in_sizes, int n_in,
                              void* d_out, int out_size, void* d_ws, size_t ws_size,
                              hipStream_t stream) {
    const float* X    = (const float*)d_in[0];
    const float* adj  = (const float*)d_in[1];
    const float* W1   = (const float*)d_in[2];
    const float* b1   = (const float*)d_in[3];
    const float* W2   = (const float*)d_in[4];
    const float* b2   = (const float*)d_in[5];
    const float* W3   = (const float*)d_in[6];
    const float* b3   = (const float*)d_in[7];
    const float* Wfc  = (const float*)d_in[8];
    const float* bfc  = (const float*)d_in[9];
    const float* Wout = (const float*)d_in[10];
    const float* bout = (const float*)d_in[11];
    float* out = (float*)d_out;

    // workspace layout (overlays exploit liveness):
    //   adjB  bf16 [4096][4096]                 32 MB
    //   P1    bf16  4 MB : H0 [384][4096] then H2 [512][4096]
    //   P2          6 MB : H1 bf16 [512][4096] then H3 fp32 [384][4096]
    //   C     fp32 [4096][512]                   8 MB
    //   hid   fp32 [128][54]
    char* w = (char*)d_ws;
    __bf16* adjB = (__bf16*)w;
    __bf16* P1   = (__bf16*)(w + 33554432);
    char*   P2   = w + 33554432 + 4194304;
    float*  C    = (float*)(w + 33554432 + 4194304 + 6291456);
    float*  hid  = (float*)(w + 33554432 + 4194304 + 6291456 + 8388608);

    __bf16* H0 = P1;
    __bf16* H1 = (__bf16*)P2;
    __bf16* H2 = P1;
    float*  H3 = (float*)P2;

    cast_adj_k<<<8192, 256, 0, stream>>>(adj, adjB);
    build_h0_k<<<1536 * 4, 256, 0, stream>>>(X, H0);   // 384*4096/256 = 6144

    // stage 1: C = adjB @ H0^T  (Nc=384)
    gemm_k<<<dim3(6, 64), 256, 0, stream>>>(adjB, H0, C, 384);
    epi_k<3, 4, __bf16><<<dim3(16, 128), 256, 0, stream>>>(C, W1, b1, H1, 384);

    // stage 2: C = adjB @ H1^T  (Nc=512)
    gemm_k<<<dim3(8, 64), 256, 0, stream>>>(adjB, H1, C, 512);
    epi_k<4, 4, __bf16><<<dim3(16, 128), 256, 0, stream>>>(C, W2, b2, H2, 512);

    // stage 3: C = adjB @ H2^T  (Nc=512)
    gemm_k<<<dim3(8, 64), 256, 0, stream>>>(adjB, H2, C, 512);
    epi_k<4, 3, float><<<dim3(16, 128), 256, 0, stream>>>(C, W3, b3, H3, 512);

    // FC head
    fc1_k<<<32, 256, 0, stream>>>(H3, Wfc, bfc, hid);
    fc2_k<<<dim3(16, 32), 256, 0, stream>>>(hid, Wout, bout, out);
}

// Round 2
// 336.829 us; speedup vs baseline: 1.7443x; 1.7443x over previous
//
#include <hip/hip_runtime.h>

// ---------------------------------------------------------------------------
// sxsGCN: h=[B=128,N=4096,3]; 3x { relu((adj@h)@W+b) }; then FC 12288->54->4096
// Strategy: bf16 MFMA GEMMs adj[4096x4096] @ H[4096 x B*F], H stored transposed
// [c = b*F+f][m] so B-operand staging is contiguous along K.
// R1: fc1 parallelized as split-K partial sums + atomicAdd (was 275us @ 1.5%
// occupancy with grid=32; now 512 blocks).
// ---------------------------------------------------------------------------

typedef __bf16 bf16x8 __attribute__((ext_vector_type(8)));
typedef float  f32x4  __attribute__((ext_vector_type(4)));

#define N_NODE 4096
#define BATCH  128

__device__ __forceinline__ void async_copy16(const void* gsrc, void* ldst) {
    __builtin_amdgcn_global_load_lds(
        (const __attribute__((address_space(1))) void*)gsrc,
        (__attribute__((address_space(3))) void*)ldst,
        16, 0, 0);
}

// adj fp32 -> bf16, 8 elems/thread
__global__ __launch_bounds__(256) void cast_adj_k(const float* __restrict__ A,
                                                  __bf16* __restrict__ AB) {
    const size_t i = (size_t)blockIdx.x * 256 + threadIdx.x;   // i-th group of 8
    const float4* a4 = (const float4*)A;
    float4 u = a4[i * 2];
    float4 v = a4[i * 2 + 1];
    bf16x8 o = { (__bf16)u.x, (__bf16)u.y, (__bf16)u.z, (__bf16)u.w,
                 (__bf16)v.x, (__bf16)v.y, (__bf16)v.z, (__bf16)v.w };
    *(bf16x8*)(AB + i * 8) = o;
}

// H0[c= b*3+f][m] = bf16(X[b][m*3+f]);  384*4096 elems, 1 per thread
__global__ __launch_bounds__(256) void build_h0_k(const float* __restrict__ X,
                                                  __bf16* __restrict__ H0) {
    const int idx = blockIdx.x * 256 + threadIdx.x;  // < 384*4096
    const int c = idx >> 12, m = idx & 4095;
    const int b = c / 3, f = c - b * 3;
    H0[idx] = (__bf16)X[(size_t)b * 12288 + m * 3 + f];
}

// C[m][c] = sum_k adjB[m][k] * Ht[c][k];  tile 64x64, 4 waves of 32x32.
// A-frag: A[m=lane&15][k=quad*8+j]; B-frag: B[k=quad*8+j][n=lane&15];
// C/D: col=lane&15, row=quad*4+reg  (learn_hip m89-verified layouts).
__global__ __launch_bounds__(256) void gemm_k(const __bf16* __restrict__ A,
                                              const __bf16* __restrict__ Bt,
                                              float* __restrict__ C, int Nc) {
    __shared__ __align__(16) __bf16 As[64 * 32];
    __shared__ __align__(16) __bf16 Bs[64 * 32];
    const int tx   = threadIdx.x;
    const int wave = tx >> 6, lane = tx & 63;
    const int quad = lane >> 4, lr = lane & 15;
    const int m0 = blockIdx.y * 64;
    const int c0 = blockIdx.x * 64;
    const int wm = wave >> 1, wn = wave & 1;   // 32x32 quadrant per wave

    // staging: thread t loads 16B for LDS byte offset t*16 (row t/4, k=(t%4)*8)
    const int srow  = tx >> 2;
    const int skoff = (tx & 3) * 8;
    const __bf16* gA = A  + (size_t)(m0 + srow) * 4096 + skoff;
    const __bf16* gB = Bt + (size_t)(c0 + srow) * 4096 + skoff;
    __bf16* lA = As + wave * 512;   // wave-uniform base; lane lands at +lane*16B
    __bf16* lB = Bs + wave * 512;

    f32x4 acc[2][2] = {};

    for (int k0 = 0; k0 < 4096; k0 += 32) {
        __syncthreads();                 // protect LDS against prior iter reads
        async_copy16(gA + k0, lA);
        async_copy16(gB + k0, lB);
        __syncthreads();                 // drains vmcnt -> LDS tiles ready
#pragma unroll
        for (int i = 0; i < 2; ++i) {
            bf16x8 af = *(const bf16x8*)(As + (wm * 32 + i * 16 + lr) * 32 + quad * 8);
#pragma unroll
            for (int j = 0; j < 2; ++j) {
                bf16x8 bfv = *(const bf16x8*)(Bs + (wn * 32 + j * 16 + lr) * 32 + quad * 8);
                acc[i][j] = __builtin_amdgcn_mfma_f32_16x16x32_bf16(af, bfv, acc[i][j], 0, 0, 0);
            }
        }
    }

#pragma unroll
    for (int i = 0; i < 2; ++i)
#pragma unroll
        for (int j = 0; j < 2; ++j)
#pragma unroll
            for (int r = 0; r < 4; ++r) {
                const int row = m0 + wm * 32 + i * 16 + quad * 4 + r;
                const int col = c0 + wn * 32 + j * 16 + lr;
                C[(size_t)row * Nc + col] = acc[i][j][r];
            }
}

// Hout[(b*FO+fo)][m] = relu( sum_fi C[m][b*FI+fi] * W[fi][fo] + bias[fo] )
template <int FI, int FO, typename OUT_T>
__global__ __launch_bounds__(256) void epi_k(const float* __restrict__ C,
                                             const float* __restrict__ W,
                                             const float* __restrict__ bias,
                                             OUT_T* __restrict__ Hout, int Ncin) {
    const int m = blockIdx.x * 256 + threadIdx.x;
    const int b = blockIdx.y;
    float in[FI];
#pragma unroll
    for (int fi = 0; fi < FI; ++fi) in[fi] = C[(size_t)m * Ncin + b * FI + fi];
#pragma unroll
    for (int fo = 0; fo < FO; ++fo) {
        float v = bias[fo];
#pragma unroll
        for (int fi = 0; fi < FI; ++fi) v += in[fi] * W[fi * FO + fo];
        v = fmaxf(v, 0.f);
        Hout[(size_t)(b * FO + fo) * N_NODE + m] = (OUT_T)v;
    }
}

// zero the fc1 accumulator (ws is poisoned 0xAA before every launch)
__global__ __launch_bounds__(256) void zero_hid_k(float* __restrict__ p) {
    const int i = blockIdx.x * 256 + threadIdx.x;
    if (i < BATCH * 54) p[i] = 0.f;
}

// fc1 split-K partial sums: grid (64 n-chunks, 8 b-groups of 16).
// Each block: stage H3 chunk [16b][3f][64n] in LDS, lanes j<54 read Wfc
// coalesced, accumulate 16 batch partials, LDS-reduce over 4 waves (each wave
// owns 16 of the 64 n), one atomicAdd per (b,j).
__global__ __launch_bounds__(256) void fc1p_k(const float* __restrict__ H3,
                                              const float* __restrict__ Wfc,
                                              float* __restrict__ hid_acc) {
    __shared__ float hs[16 * 192];       // [b][f][n] = b*192 + f*64 + n
    __shared__ float red[4][16][64];
    const int tx = threadIdx.x;
    const int wv = tx >> 6, lane = tx & 63;
    const int n0 = blockIdx.x * 64;
    const int b0 = blockIdx.y * 16;

    for (int idx = tx; idx < 3072; idx += 256) {
        const int n = idx & 63, f = (idx >> 6) % 3, b = idx / 192;
        hs[idx] = H3[((size_t)((b0 + b) * 3 + f)) * N_NODE + n0 + n];
    }
    __syncthreads();

    float acc[16];
#pragma unroll
    for (int b = 0; b < 16; ++b) acc[b] = 0.f;
    if (lane < 54) {
        const int nb = wv * 16;
        for (int n = 0; n < 16; ++n) {
#pragma unroll
            for (int f = 0; f < 3; ++f) {
                const float w = Wfc[((size_t)(n0 + nb + n) * 3 + f) * 54 + lane];
#pragma unroll
                for (int b = 0; b < 16; ++b)
                    acc[b] += hs[b * 192 + f * 64 + nb + n] * w;
            }
        }
    }
#pragma unroll
    for (int b = 0; b < 16; ++b) red[wv][b][lane] = acc[b];
    __syncthreads();
    if (wv == 0 && lane < 54) {
        for (int b = 0; b < 16; ++b) {
            const float s = red[0][b][lane] + red[1][b][lane] +
                            red[2][b][lane] + red[3][b][lane];
            atomicAdd(&hid_acc[(b0 + b) * 54 + lane], s);
        }
    }
}

// hid = relu(hid_acc + bfc)
__global__ __launch_bounds__(256) void fc1fix_k(float* __restrict__ hid,
                                                const float* __restrict__ bfc) {
    const int i = blockIdx.x * 256 + threadIdx.x;
    if (i < BATCH * 54) {
        const int j = i % 54;
        hid[i] = fmaxf(hid[i] + bfc[j], 0.f);
    }
}

// out[b][a] = sum_j hid[b][j]*Wout[j][a] + bout[a];  4 batches/block
__global__ __launch_bounds__(256) void fc2_k(const float* __restrict__ hid,
                                             const float* __restrict__ Wout,
                                             const float* __restrict__ bout,
                                             float* __restrict__ out) {
    const int tx = threadIdx.x;
    const int a  = blockIdx.x * 256 + tx;
    const int b0 = blockIdx.y * 4;
    __shared__ float hs[4 * 54];
    if (tx < 216) hs[tx] = hid[b0 * 54 + tx];
    __syncthreads();
    float a0 = 0.f, a1 = 0.f, a2 = 0.f, a3 = 0.f;
    for (int j = 0; j < 54; ++j) {
        float w = Wout[(size_t)j * N_NODE + a];
        a0 += hs[0 * 54 + j] * w;
        a1 += hs[1 * 54 + j] * w;
        a2 += hs[2 * 54 + j] * w;
        a3 += hs[3 * 54 + j] * w;
    }
    float bo = bout[a];
    out[(size_t)(b0 + 0) * N_NODE + a] = a0 + bo;
    out[(size_t)(b0 + 1) * N_NODE + a] = a1 + bo;
    out[(size_t)(b0 + 2) * N_NODE + a] = a2 + bo;
    out[(size_t)(b0 + 3) * N_NODE + a] = a3 + bo;
}

extern "C" void kernel_launch(void* const* d_in, const int* in_sizes, int n_in,
                              void* d_out, int out_size, void* d_ws, size_t ws_size,
                              hipStream_t stream) {
    const float* X    = (const float*)d_in[0];
    const float* adj  = (const float*)d_in[1];
    const float* W1   = (const float*)d_in[2];
    const float* b1   = (const float*)d_in[3];
    const float* W2   = (const float*)d_in[4];
    const float* b2   = (const float*)d_in[5];
    const float* W3   = (const float*)d_in[6];
    const float* b3   = (const float*)d_in[7];
    const float* Wfc  = (const float*)d_in[8];
    const float* bfc  = (const float*)d_in[9];
    const float* Wout = (const float*)d_in[10];
    const float* bout = (const float*)d_in[11];
    float* out = (float*)d_out;

    // workspace layout (overlays exploit liveness):
    //   adjB  bf16 [4096][4096]                 32 MB
    //   P1    bf16  4 MB : H0 [384][4096] then H2 [512][4096]
    //   P2          6 MB : H1 bf16 [512][4096] then H3 fp32 [384][4096]
    //   C     fp32 [4096][512]                   8 MB
    //   hid   fp32 [128][54]  (fc1 accumulator, fixed up in place)
    char* w = (char*)d_ws;
    __bf16* adjB = (__bf16*)w;
    __bf16* P1   = (__bf16*)(w + 33554432);
    char*   P2   = w + 33554432 + 4194304;
    float*  C    = (float*)(w + 33554432 + 4194304 + 6291456);
    float*  hid  = (float*)(w + 33554432 + 4194304 + 6291456 + 8388608);

    __bf16* H0 = P1;
    __bf16* H1 = (__bf16*)P2;
    __bf16* H2 = P1;
    float*  H3 = (float*)P2;

    cast_adj_k<<<8192, 256, 0, stream>>>(adj, adjB);
    build_h0_k<<<1536 * 4, 256, 0, stream>>>(X, H0);   // 384*4096/256 = 6144
    zero_hid_k<<<27, 256, 0, stream>>>(hid);           // early: off critical path

    // stage 1: C = adjB @ H0^T  (Nc=384)
    gemm_k<<<dim3(6, 64), 256, 0, stream>>>(adjB, H0, C, 384);
    epi_k<3, 4, __bf16><<<dim3(16, 128), 256, 0, stream>>>(C, W1, b1, H1, 384);

    // stage 2: C = adjB @ H1^T  (Nc=512)
    gemm_k<<<dim3(8, 64), 256, 0, stream>>>(adjB, H1, C, 512);
    epi_k<4, 4, __bf16><<<dim3(16, 128), 256, 0, stream>>>(C, W2, b2, H2, 512);

    // stage 3: C = adjB @ H2^T  (Nc=512)
    gemm_k<<<dim3(8, 64), 256, 0, stream>>>(adjB, H2, C, 512);
    epi_k<4, 3, float><<<dim3(16, 128), 256, 0, stream>>>(C, W3, b3, H3, 512);

    // FC head: split-K partials + atomics, then bias+relu, then fc2
    fc1p_k<<<dim3(64, 8), 256, 0, stream>>>(H3, Wfc, hid);
    fc1fix_k<<<27, 256, 0, stream>>>(hid, bfc);
    fc2_k<<<dim3(16, 32), 256, 0, stream>>>(hid, Wout, bout, out);
}

// Round 3
// 295.739 us; speedup vs baseline: 1.9866x; 1.1389x over previous
//
#include <hip/hip_runtime.h>

// ---------------------------------------------------------------------------
// sxsGCN: h=[B=128,N=4096,3]; 3x { relu((adj@h)@W+b) }; then FC 12288->54->4096
// Strategy: bf16 MFMA GEMMs adj[4096x4096] @ H[4096 x B*F], H stored transposed
// [c = b*F+f][m] so B-operand staging is contiguous along K.
// R1: fc1 parallelized (split-K + atomics): 275us -> ~10us.
// R2: gemm_k double-buffered, BK=64. Old loop was synchronous (load->drain->
// 4 MFMAs, 128 iters, global latency exposed every iter -> 62us @ MfmaUtil 10%).
// K-tile stored as two [64][32] half-tiles: keeps global_load_lds lane
// contiguity AND the 32-bank-covering 64B row stride for ds_read_b128.
// ---------------------------------------------------------------------------

typedef __bf16 bf16x8 __attribute__((ext_vector_type(8)));
typedef float  f32x4  __attribute__((ext_vector_type(4)));

#define N_NODE 4096
#define BATCH  128

__device__ __forceinline__ void async_copy16(const void* gsrc, void* ldst) {
    __builtin_amdgcn_global_load_lds(
        (const __attribute__((address_space(1))) void*)gsrc,
        (__attribute__((address_space(3))) void*)ldst,
        16, 0, 0);
}

// adj fp32 -> bf16, 8 elems/thread
__global__ __launch_bounds__(256) void cast_adj_k(const float* __restrict__ A,
                                                  __bf16* __restrict__ AB) {
    const size_t i = (size_t)blockIdx.x * 256 + threadIdx.x;   // i-th group of 8
    const float4* a4 = (const float4*)A;
    float4 u = a4[i * 2];
    float4 v = a4[i * 2 + 1];
    bf16x8 o = { (__bf16)u.x, (__bf16)u.y, (__bf16)u.z, (__bf16)u.w,
                 (__bf16)v.x, (__bf16)v.y, (__bf16)v.z, (__bf16)v.w };
    *(bf16x8*)(AB + i * 8) = o;
}

// H0[c= b*3+f][m] = bf16(X[b][m*3+f]);  384*4096 elems, 1 per thread
__global__ __launch_bounds__(256) void build_h0_k(const float* __restrict__ X,
                                                  __bf16* __restrict__ H0) {
    const int idx = blockIdx.x * 256 + threadIdx.x;  // < 384*4096
    const int c = idx >> 12, m = idx & 4095;
    const int b = c / 3, f = c - b * 3;
    H0[idx] = (__bf16)X[(size_t)b * 12288 + m * 3 + f];
}

// C[m][c] = sum_k adjB[m][k] * Ht[c][k];  tile 64x64, 4 waves of 32x32,
// BK=64 double-buffered. A-frag: A[m=lane&15][k=quad*8+j]; B-frag:
// B[k=quad*8+j][n=lane&15]; C/D: col=lane&15, row=quad*4+reg.
__global__ __launch_bounds__(256) void gemm_k(const __bf16* __restrict__ A,
                                              const __bf16* __restrict__ Bt,
                                              float* __restrict__ C, int Nc) {
    // [buf][khalf][64 rows][32 k]
    __shared__ __align__(16) __bf16 As[2][2][2048];
    __shared__ __align__(16) __bf16 Bs[2][2][2048];
    const int tx   = threadIdx.x;
    const int wave = tx >> 6, lane = tx & 63;
    const int quad = lane >> 4, lr = lane & 15;
    const int m0 = blockIdx.y * 64;
    const int c0 = blockIdx.x * 64;
    const int wm = wave >> 1, wn = wave & 1;   // 32x32 quadrant per wave

    // staging: thread t copies one 16B chunk per (matrix, khalf):
    // chunk t -> row t>>2, k-chunk t&3; LDS slot = t*16B (lane-contiguous).
    const int srow  = tx >> 2;
    const int skoff = (tx & 3) * 8;
    const __bf16* gA = A  + (size_t)(m0 + srow) * 4096 + skoff;
    const __bf16* gB = Bt + (size_t)(c0 + srow) * 4096 + skoff;
    __bf16* lA0_ = &As[0][0][tx * 8];  __bf16* lA1_ = &As[0][1][tx * 8];
    __bf16* lB0_ = &Bs[0][0][tx * 8];  __bf16* lB1_ = &Bs[0][1][tx * 8];
    const int bufstride = 4096;        // elems between buf 0 and buf 1

    f32x4 acc[2][2] = {};

    // prologue: stage tile 0 into buf 0
    async_copy16(gA,      lA0_);
    async_copy16(gA + 32, lA1_);
    async_copy16(gB,      lB0_);
    async_copy16(gB + 32, lB1_);

    int buf = 0;
    for (int kt = 0; kt < 64; ++kt) {
        __syncthreads();   // drains vmcnt -> buf ready; prev reads of buf^1 done
        if (kt + 1 < 64) {
            const int ko = (kt + 1) * 64;
            const int bo = (buf ^ 1) * bufstride;
            async_copy16(gA + ko,      lA0_ + bo);
            async_copy16(gA + ko + 32, lA1_ + bo);
            async_copy16(gB + ko,      lB0_ + bo);
            async_copy16(gB + ko + 32, lB1_ + bo);
        }
#pragma unroll
        for (int kh = 0; kh < 2; ++kh) {
#pragma unroll
            for (int i = 0; i < 2; ++i) {
                bf16x8 af = *(const bf16x8*)(&As[buf][kh][(wm * 32 + i * 16 + lr) * 32 + quad * 8]);
#pragma unroll
                for (int j = 0; j < 2; ++j) {
                    bf16x8 bfv = *(const bf16x8*)(&Bs[buf][kh][(wn * 32 + j * 16 + lr) * 32 + quad * 8]);
                    acc[i][j] = __builtin_amdgcn_mfma_f32_16x16x32_bf16(af, bfv, acc[i][j], 0, 0, 0);
                }
            }
        }
        buf ^= 1;
    }

#pragma unroll
    for (int i = 0; i < 2; ++i)
#pragma unroll
        for (int j = 0; j < 2; ++j)
#pragma unroll
            for (int r = 0; r < 4; ++r) {
                const int row = m0 + wm * 32 + i * 16 + quad * 4 + r;
                const int col = c0 + wn * 32 + j * 16 + lr;
                C[(size_t)row * Nc + col] = acc[i][j][r];
            }
}

// Hout[(b*FO+fo)][m] = relu( sum_fi C[m][b*FI+fi] * W[fi][fo] + bias[fo] )
template <int FI, int FO, typename OUT_T>
__global__ __launch_bounds__(256) void epi_k(const float* __restrict__ C,
                                             const float* __restrict__ W,
                                             const float* __restrict__ bias,
                                             OUT_T* __restrict__ Hout, int Ncin) {
    const int m = blockIdx.x * 256 + threadIdx.x;
    const int b = blockIdx.y;
    float in[FI];
#pragma unroll
    for (int fi = 0; fi < FI; ++fi) in[fi] = C[(size_t)m * Ncin + b * FI + fi];
#pragma unroll
    for (int fo = 0; fo < FO; ++fo) {
        float v = bias[fo];
#pragma unroll
        for (int fi = 0; fi < FI; ++fi) v += in[fi] * W[fi * FO + fo];
        v = fmaxf(v, 0.f);
        Hout[(size_t)(b * FO + fo) * N_NODE + m] = (OUT_T)v;
    }
}

// zero the fc1 accumulator (ws is poisoned 0xAA before every launch)
__global__ __launch_bounds__(256) void zero_hid_k(float* __restrict__ p) {
    const int i = blockIdx.x * 256 + threadIdx.x;
    if (i < BATCH * 54) p[i] = 0.f;
}

// fc1 split-K partial sums: grid (64 n-chunks, 8 b-groups of 16).
__global__ __launch_bounds__(256) void fc1p_k(const float* __restrict__ H3,
                                              const float* __restrict__ Wfc,
                                              float* __restrict__ hid_acc) {
    __shared__ float hs[16 * 192];       // [b][f][n] = b*192 + f*64 + n
    __shared__ float red[4][16][64];
    const int tx = threadIdx.x;
    const int wv = tx >> 6, lane = tx & 63;
    const int n0 = blockIdx.x * 64;
    const int b0 = blockIdx.y * 16;

    for (int idx = tx; idx < 3072; idx += 256) {
        const int n = idx & 63, f = (idx >> 6) % 3, b = idx / 192;
        hs[idx] = H3[((size_t)((b0 + b) * 3 + f)) * N_NODE + n0 + n];
    }
    __syncthreads();

    float acc[16];
#pragma unroll
    for (int b = 0; b < 16; ++b) acc[b] = 0.f;
    if (lane < 54) {
        const int nb = wv * 16;
        for (int n = 0; n < 16; ++n) {
#pragma unroll
            for (int f = 0; f < 3; ++f) {
                const float w = Wfc[((size_t)(n0 + nb + n) * 3 + f) * 54 + lane];
#pragma unroll
                for (int b = 0; b < 16; ++b)
                    acc[b] += hs[b * 192 + f * 64 + nb + n] * w;
            }
        }
    }
#pragma unroll
    for (int b = 0; b < 16; ++b) red[wv][b][lane] = acc[b];
    __syncthreads();
    if (wv == 0 && lane < 54) {
        for (int b = 0; b < 16; ++b) {
            const float s = red[0][b][lane] + red[1][b][lane] +
                            red[2][b][lane] + red[3][b][lane];
            atomicAdd(&hid_acc[(b0 + b) * 54 + lane], s);
        }
    }
}

// hid = relu(hid_acc + bfc)
__global__ __launch_bounds__(256) void fc1fix_k(float* __restrict__ hid,
                                                const float* __restrict__ bfc) {
    const int i = blockIdx.x * 256 + threadIdx.x;
    if (i < BATCH * 54) {
        const int j = i % 54;
        hid[i] = fmaxf(hid[i] + bfc[j], 0.f);
    }
}

// out[b][a] = sum_j hid[b][j]*Wout[j][a] + bout[a];  4 batches/block
__global__ __launch_bounds__(256) void fc2_k(const float* __restrict__ hid,
                                             const float* __restrict__ Wout,
                                             const float* __restrict__ bout,
                                             float* __restrict__ out) {
    const int tx = threadIdx.x;
    const int a  = blockIdx.x * 256 + tx;
    const int b0 = blockIdx.y * 4;
    __shared__ float hs[4 * 54];
    if (tx < 216) hs[tx] = hid[b0 * 54 + tx];
    __syncthreads();
    float a0 = 0.f, a1 = 0.f, a2 = 0.f, a3 = 0.f;
    for (int j = 0; j < 54; ++j) {
        float w = Wout[(size_t)j * N_NODE + a];
        a0 += hs[0 * 54 + j] * w;
        a1 += hs[1 * 54 + j] * w;
        a2 += hs[2 * 54 + j] * w;
        a3 += hs[3 * 54 + j] * w;
    }
    float bo = bout[a];
    out[(size_t)(b0 + 0) * N_NODE + a] = a0 + bo;
    out[(size_t)(b0 + 1) * N_NODE + a] = a1 + bo;
    out[(size_t)(b0 + 2) * N_NODE + a] = a2 + bo;
    out[(size_t)(b0 + 3) * N_NODE + a] = a3 + bo;
}

extern "C" void kernel_launch(void* const* d_in, const int* in_sizes, int n_in,
                              void* d_out, int out_size, void* d_ws, size_t ws_size,
                              hipStream_t stream) {
    const float* X    = (const float*)d_in[0];
    const float* adj  = (const float*)d_in[1];
    const float* W1   = (const float*)d_in[2];
    const float* b1   = (const float*)d_in[3];
    const float* W2   = (const float*)d_in[4];
    const float* b2   = (const float*)d_in[5];
    const float* W3   = (const float*)d_in[6];
    const float* b3   = (const float*)d_in[7];
    const float* Wfc  = (const float*)d_in[8];
    const float* bfc  = (const float*)d_in[9];
    const float* Wout = (const float*)d_in[10];
    const float* bout = (const float*)d_in[11];
    float* out = (float*)d_out;

    // workspace layout (overlays exploit liveness):
    //   adjB  bf16 [4096][4096]                 32 MB
    //   P1    bf16  4 MB : H0 [384][4096] then H2 [512][4096]
    //   P2          6 MB : H1 bf16 [512][4096] then H3 fp32 [384][4096]
    //   C     fp32 [4096][512]                   8 MB
    //   hid   fp32 [128][54]  (fc1 accumulator, fixed up in place)
    char* w = (char*)d_ws;
    __bf16* adjB = (__bf16*)w;
    __bf16* P1   = (__bf16*)(w + 33554432);
    char*   P2   = w + 33554432 + 4194304;
    float*  C    = (float*)(w + 33554432 + 4194304 + 6291456);
    float*  hid  = (float*)(w + 33554432 + 4194304 + 6291456 + 8388608);

    __bf16* H0 = P1;
    __bf16* H1 = (__bf16*)P2;
    __bf16* H2 = P1;
    float*  H3 = (float*)P2;

    cast_adj_k<<<8192, 256, 0, stream>>>(adj, adjB);
    build_h0_k<<<1536 * 4, 256, 0, stream>>>(X, H0);   // 384*4096/256 = 6144
    zero_hid_k<<<27, 256, 0, stream>>>(hid);           // early: off critical path

    // stage 1: C = adjB @ H0^T  (Nc=384)
    gemm_k<<<dim3(6, 64), 256, 0, stream>>>(adjB, H0, C, 384);
    epi_k<3, 4, __bf16><<<dim3(16, 128), 256, 0, stream>>>(C, W1, b1, H1, 384);

    // stage 2: C = adjB @ H1^T  (Nc=512)
    gemm_k<<<dim3(8, 64), 256, 0, stream>>>(adjB, H1, C, 512);
    epi_k<4, 4, __bf16><<<dim3(16, 128), 256, 0, stream>>>(C, W2, b2, H2, 512);

    // stage 3: C = adjB @ H2^T  (Nc=512)
    gemm_k<<<dim3(8, 64), 256, 0, stream>>>(adjB, H2, C, 512);
    epi_k<4, 3, float><<<dim3(16, 128), 256, 0, stream>>>(C, W3, b3, H3, 512);

    // FC head: split-K partials + atomics, then bias+relu, then fc2
    fc1p_k<<<dim3(64, 8), 256, 0, stream>>>(H3, Wfc, hid);
    fc1fix_k<<<27, 256, 0, stream>>>(hid, bfc);
    fc2_k<<<dim3(16, 32), 256, 0, stream>>>(hid, Wout, bout, out);
}

// Round 4
// 289.590 us; speedup vs baseline: 2.0288x; 1.0212x over previous
//
#include <hip/hip_runtime.h>

// ---------------------------------------------------------------------------
// sxsGCN: h=[B=128,N=4096,3]; 3x { relu((adj@h)@W+b) }; then FC 12288->54->4096
// Strategy: bf16 MFMA GEMMs adj[4096x4096] @ H[4096 x B*F], H stored transposed
// [c = b*F+f][m] so B-operand staging is contiguous along K.
// R1: fc1 parallelized (split-K + atomics): 275us -> ~10us.
// R2: gemm_k double-buffered BK=64: 62 -> 47us. Conflicts 4.2e6 (8-way: 64B row
//     stride aliases 16-lane frag reads onto 4 banks), B-frags read 2x.
// R3: XOR-swizzled k-chunk placement (pos=(chunk+(row>>1))&3 -> 2 lanes/bank =
//     free), hoisted B reads (12->8KB/wave/iter), coalesced transpose epilogue,
//     fused fc1fix->fc2 and zero_hid->build_h0 (13->10 dispatches).
// ---------------------------------------------------------------------------

typedef __bf16 bf16x8 __attribute__((ext_vector_type(8)));
typedef float  f32x4  __attribute__((ext_vector_type(4)));

#define N_NODE 4096
#define BATCH  128

__device__ __forceinline__ void async_copy16(const void* gsrc, void* ldst) {
    __builtin_amdgcn_global_load_lds(
        (const __attribute__((address_space(1))) void*)gsrc,
        (__attribute__((address_space(3))) void*)ldst,
        16, 0, 0);
}

// adj fp32 -> bf16, 8 elems/thread
__global__ __launch_bounds__(256) void cast_adj_k(const float* __restrict__ A,
                                                  __bf16* __restrict__ AB) {
    const size_t i = (size_t)blockIdx.x * 256 + threadIdx.x;   // i-th group of 8
    const float4* a4 = (const float4*)A;
    float4 u = a4[i * 2];
    float4 v = a4[i * 2 + 1];
    bf16x8 o = { (__bf16)u.x, (__bf16)u.y, (__bf16)u.z, (__bf16)u.w,
                 (__bf16)v.x, (__bf16)v.y, (__bf16)v.z, (__bf16)v.w };
    *(bf16x8*)(AB + i * 8) = o;
}

// H0[c= b*3+f][m] = bf16(X[b][m*3+f]); also zero the fc1 accumulator.
__global__ __launch_bounds__(256) void build_h0_k(const float* __restrict__ X,
                                                  __bf16* __restrict__ H0,
                                                  float* __restrict__ hid_acc) {
    const int idx = blockIdx.x * 256 + threadIdx.x;  // < 384*4096
    if (blockIdx.x < 27) hid_acc[idx] = 0.f;         // 27*256 == 128*54
    const int c = idx >> 12, m = idx & 4095;
    const int b = c / 3, f = c - b * 3;
    H0[idx] = (__bf16)X[(size_t)b * 12288 + m * 3 + f];
}

// C[m][c] = sum_k adjB[m][k] * Ht[c][k];  tile 64x64, 4 waves of 32x32,
// BK=64 double-buffered, XOR-swizzled chunk placement.
// A-frag: A[m=lane&15][k=quad*8+j]; B-frag: B[k=quad*8+j][n=lane&15];
// C/D: col=lane&15, row=quad*4+reg.
__global__ __launch_bounds__(256) void gemm_k(const __bf16* __restrict__ A,
                                              const __bf16* __restrict__ Bt,
                                              float* __restrict__ C, int Nc) {
    // [buf][khalf][row 64][k 32], 16B chunk of logical k-chunk c stored at
    // position p = (c + (row>>1)) & 3 within the row.
    __shared__ __align__(16) __bf16 As[2][2][2048];
    __shared__ __align__(16) __bf16 Bs[2][2][2048];
    const int tx   = threadIdx.x;
    const int wave = tx >> 6, lane = tx & 63;
    const int quad = lane >> 4, lr = lane & 15;
    const int m0 = blockIdx.y * 64;
    const int c0 = blockIdx.x * 64;
    const int wm = wave >> 1, wn = wave & 1;   // 32x32 quadrant per wave

    // staging: thread t owns LDS slot t*16B = (row=t>>2, pos=t&3); it must
    // fetch logical chunk c = (pos - (row>>1)) & 3 of its row.
    const int srow   = tx >> 2;
    const int schunk = ((tx & 3) - (srow >> 1)) & 3;
    const int skoff  = schunk * 8;
    const __bf16* gA = A  + (size_t)(m0 + srow) * 4096 + skoff;
    const __bf16* gB = Bt + (size_t)(c0 + srow) * 4096 + skoff;
    __bf16* lA0_ = &As[0][0][tx * 8];  __bf16* lA1_ = &As[0][1][tx * 8];
    __bf16* lB0_ = &Bs[0][0][tx * 8];  __bf16* lB1_ = &Bs[0][1][tx * 8];
    const int bufstride = 4096;        // elems between buf 0 and buf 1

    // reader swizzle position: (quad + (row>>1))&3 with row = *+16i+lr, and
    // the *,i parts are 0 mod 4 after >>1 -> independent of i/kh/wm/wn.
    const int pos = (quad + (lr >> 1)) & 3;
    const int arow0 = (wm * 32 + lr) * 32 + pos * 8;       // i=0
    const int brow0 = (wn * 32 + lr) * 32 + pos * 8;       // j=0

    f32x4 acc[2][2] = {};

    // prologue: stage tile 0 into buf 0
    async_copy16(gA,      lA0_);
    async_copy16(gA + 32, lA1_);
    async_copy16(gB,      lB0_);
    async_copy16(gB + 32, lB1_);

    int buf = 0;
    for (int kt = 0; kt < 64; ++kt) {
        __syncthreads();   // drains vmcnt -> buf ready; prev reads of buf^1 done
        if (kt + 1 < 64) {
            const int ko = (kt + 1) * 64;
            const int bo = (buf ^ 1) * bufstride;
            async_copy16(gA + ko,      lA0_ + bo);
            async_copy16(gA + ko + 32, lA1_ + bo);
            async_copy16(gB + ko,      lB0_ + bo);
            async_copy16(gB + ko + 32, lB1_ + bo);
        }
#pragma unroll
        for (int kh = 0; kh < 2; ++kh) {
            bf16x8 a0  = *(const bf16x8*)(&As[buf][kh][arow0]);
            bf16x8 a1  = *(const bf16x8*)(&As[buf][kh][arow0 + 16 * 32]);
            bf16x8 b0v = *(const bf16x8*)(&Bs[buf][kh][brow0]);
            bf16x8 b1v = *(const bf16x8*)(&Bs[buf][kh][brow0 + 16 * 32]);
            acc[0][0] = __builtin_amdgcn_mfma_f32_16x16x32_bf16(a0, b0v, acc[0][0], 0, 0, 0);
            acc[0][1] = __builtin_amdgcn_mfma_f32_16x16x32_bf16(a0, b1v, acc[0][1], 0, 0, 0);
            acc[1][0] = __builtin_amdgcn_mfma_f32_16x16x32_bf16(a1, b0v, acc[1][0], 0, 0, 0);
            acc[1][1] = __builtin_amdgcn_mfma_f32_16x16x32_bf16(a1, b1v, acc[1][1], 0, 0, 0);
        }
        buf ^= 1;
    }

#pragma unroll
    for (int i = 0; i < 2; ++i)
#pragma unroll
        for (int j = 0; j < 2; ++j)
#pragma unroll
            for (int r = 0; r < 4; ++r) {
                const int row = m0 + wm * 32 + i * 16 + quad * 4 + r;
                const int col = c0 + wn * 32 + j * 16 + lr;
                C[(size_t)row * Nc + col] = acc[i][j][r];
            }
}

// Coalesced transpose epilogue.
// Grid (64 m-tiles, 4 b-tiles of 32). Stage C[64 m][32b*FI] in LDS (coalesced
// row-major loads), then thread (m=tx&63, bq=tx>>6) emits FO outputs per b
// with m-contiguous (coalesced) writes of Hout[(b*FO+fo)*4096 + m].
template <int FI, int FO, typename OUT_T>
__global__ __launch_bounds__(256) void epi_k(const float* __restrict__ C,
                                             const float* __restrict__ W,
                                             const float* __restrict__ bias,
                                             OUT_T* __restrict__ Hout, int Ncin) {
    constexpr int COLS = 32 * FI;
    constexpr int S    = COLS + 1;       // odd stride -> conflict-free col reads
    __shared__ float ld[64 * S];
    const int tx = threadIdx.x;
    const int m0  = blockIdx.x * 64;
    const int bt0 = blockIdx.y * 32;

    for (int idx = tx; idx < 64 * COLS; idx += 256) {
        const int r = idx / COLS, cc = idx - r * COLS;
        ld[r * S + cc] = C[(size_t)(m0 + r) * Ncin + bt0 * FI + cc];
    }
    __syncthreads();

    const int m_l = tx & 63, bq = tx >> 6;
    float Wl[FI][FO];
#pragma unroll
    for (int fi = 0; fi < FI; ++fi)
#pragma unroll
        for (int fo = 0; fo < FO; ++fo) Wl[fi][fo] = W[fi * FO + fo];

#pragma unroll
    for (int p = 0; p < 8; ++p) {
        const int bl = bq + p * 4;       // 0..31
        float in[FI];
#pragma unroll
        for (int fi = 0; fi < FI; ++fi) in[fi] = ld[m_l * S + bl * FI + fi];
#pragma unroll
        for (int fo = 0; fo < FO; ++fo) {
            float v = bias[fo];
#pragma unroll
            for (int fi = 0; fi < FI; ++fi) v += in[fi] * Wl[fi][fo];
            v = fmaxf(v, 0.f);
            Hout[(size_t)((bt0 + bl) * FO + fo) * N_NODE + m0 + m_l] = (OUT_T)v;
        }
    }
}

// fc1 split-K partial sums: grid (64 n-chunks, 8 b-groups of 16).
__global__ __launch_bounds__(256) void fc1p_k(const float* __restrict__ H3,
                                              const float* __restrict__ Wfc,
                                              float* __restrict__ hid_acc) {
    __shared__ float hs[16 * 192];       // [b][f][n] = b*192 + f*64 + n
    __shared__ float red[4][16][64];
    const int tx = threadIdx.x;
    const int wv = tx >> 6, lane = tx & 63;
    const int n0 = blockIdx.x * 64;
    const int b0 = blockIdx.y * 16;

    for (int idx = tx; idx < 3072; idx += 256) {
        const int n = idx & 63, f = (idx >> 6) % 3, b = idx / 192;
        hs[idx] = H3[((size_t)((b0 + b) * 3 + f)) * N_NODE + n0 + n];
    }
    __syncthreads();

    float acc[16];
#pragma unroll
    for (int b = 0; b < 16; ++b) acc[b] = 0.f;
    if (lane < 54) {
        const int nb = wv * 16;
        for (int n = 0; n < 16; ++n) {
#pragma unroll
            for (int f = 0; f < 3; ++f) {
                const float w = Wfc[((size_t)(n0 + nb + n) * 3 + f) * 54 + lane];
#pragma unroll
                for (int b = 0; b < 16; ++b)
                    acc[b] += hs[b * 192 + f * 64 + nb + n] * w;
            }
        }
    }
#pragma unroll
    for (int b = 0; b < 16; ++b) red[wv][b][lane] = acc[b];
    __syncthreads();
    if (wv == 0 && lane < 54) {
        for (int b = 0; b < 16; ++b) {
            const float s = red[0][b][lane] + red[1][b][lane] +
                            red[2][b][lane] + red[3][b][lane];
            atomicAdd(&hid_acc[(b0 + b) * 54 + lane], s);
        }
    }
}

// out[b][a] = sum_j relu(hid_acc[b][j]+bfc[j]) * Wout[j][a] + bout[a]
__global__ __launch_bounds__(256) void fc2_k(const float* __restrict__ hid_acc,
                                             const float* __restrict__ bfc,
                                             const float* __restrict__ Wout,
                                             const float* __restrict__ bout,
                                             float* __restrict__ out) {
    const int tx = threadIdx.x;
    const int a  = blockIdx.x * 256 + tx;
    const int b0 = blockIdx.y * 4;
    __shared__ float hs[4 * 54];
    if (tx < 216) {
        const int j = tx % 54;
        hs[tx] = fmaxf(hid_acc[b0 * 54 + tx] + bfc[j], 0.f);
    }
    __syncthreads();
    float a0 = 0.f, a1 = 0.f, a2 = 0.f, a3 = 0.f;
    for (int j = 0; j < 54; ++j) {
        float w = Wout[(size_t)j * N_NODE + a];
        a0 += hs[0 * 54 + j] * w;
        a1 += hs[1 * 54 + j] * w;
        a2 += hs[2 * 54 + j] * w;
        a3 += hs[3 * 54 + j] * w;
    }
    float bo = bout[a];
    out[(size_t)(b0 + 0) * N_NODE + a] = a0 + bo;
    out[(size_t)(b0 + 1) * N_NODE + a] = a1 + bo;
    out[(size_t)(b0 + 2) * N_NODE + a] = a2 + bo;
    out[(size_t)(b0 + 3) * N_NODE + a] = a3 + bo;
}

extern "C" void kernel_launch(void* const* d_in, const int* in_sizes, int n_in,
                              void* d_out, int out_size, void* d_ws, size_t ws_size,
                              hipStream_t stream) {
    const float* X    = (const float*)d_in[0];
    const float* adj  = (const float*)d_in[1];
    const float* W1   = (const float*)d_in[2];
    const float* b1   = (const float*)d_in[3];
    const float* W2   = (const float*)d_in[4];
    const float* b2   = (const float*)d_in[5];
    const float* W3   = (const float*)d_in[6];
    const float* b3   = (const float*)d_in[7];
    const float* Wfc  = (const float*)d_in[8];
    const float* bfc  = (const float*)d_in[9];
    const float* Wout = (const float*)d_in[10];
    const float* bout = (const float*)d_in[11];
    float* out = (float*)d_out;

    // workspace layout (overlays exploit liveness):
    //   adjB  bf16 [4096][4096]                 32 MB
    //   P1    bf16  4 MB : H0 [384][4096] then H2 [512][4096]
    //   P2          6 MB : H1 bf16 [512][4096] then H3 fp32 [384][4096]
    //   C     fp32 [4096][512]                   8 MB
    //   hid   fp32 [128][54]  (fc1 accumulator; bias+relu fused into fc2)
    char* w = (char*)d_ws;
    __bf16* adjB = (__bf16*)w;
    __bf16* P1   = (__bf16*)(w + 33554432);
    char*   P2   = w + 33554432 + 4194304;
    float*  C    = (float*)(w + 33554432 + 4194304 + 6291456);
    float*  hid  = (float*)(w + 33554432 + 4194304 + 6291456 + 8388608);

    __bf16* H0 = P1;
    __bf16* H1 = (__bf16*)P2;
    __bf16* H2 = P1;
    float*  H3 = (float*)P2;

    cast_adj_k<<<8192, 256, 0, stream>>>(adj, adjB);
    build_h0_k<<<6144, 256, 0, stream>>>(X, H0, hid);

    // stage 1: C = adjB @ H0^T  (Nc=384)
    gemm_k<<<dim3(6, 64), 256, 0, stream>>>(adjB, H0, C, 384);
    epi_k<3, 4, __bf16><<<dim3(64, 4), 256, 0, stream>>>(C, W1, b1, H1, 384);

    // stage 2: C = adjB @ H1^T  (Nc=512)
    gemm_k<<<dim3(8, 64), 256, 0, stream>>>(adjB, H1, C, 512);
    epi_k<4, 4, __bf16><<<dim3(64, 4), 256, 0, stream>>>(C, W2, b2, H2, 512);

    // stage 3: C = adjB @ H2^T  (Nc=512)
    gemm_k<<<dim3(8, 64), 256, 0, stream>>>(adjB, H2, C, 512);
    epi_k<4, 3, float><<<dim3(64, 4), 256, 0, stream>>>(C, W3, b3, H3, 512);

    // FC head: split-K partials + atomics, then fc2 (bias+relu fused)
    fc1p_k<<<dim3(64, 8), 256, 0, stream>>>(H3, Wfc, hid);
    fc2_k<<<dim3(16, 32), 256, 0, stream>>>(hid, bfc, Wout, bout, out);
}